// Round 1
// baseline (225.692 us; speedup 1.0000x reference)
//
#include <hip/hip_runtime.h>

// QuantizedTopKSparsity on (8192, 4096) f32.
// Mathematical simplification: gamma = rowmax(|x|) => |x/(gamma+eps)| < 1,
// so x_q = round(x/(gamma+eps)) in {-1,0,1}; abs_q in {0,1}; the k-th largest
// abs value (thresh) is 0 or 1, and in BOTH cases x_q * (abs_q >= thresh) == x_q.
// Output = rintf(x / (gamma + 1e-6f)), row-wise.  Memory-bound single pass.

#define ROW_D 4096
#define BLOCK 256
#define EPS_Q 1e-6f

__global__ __launch_bounds__(BLOCK) void qtern_kernel(const float* __restrict__ x,
                                                      float* __restrict__ out) {
    const long long row = blockIdx.x;
    const float4* __restrict__ xrow =
        reinterpret_cast<const float4*>(x + row * (long long)ROW_D);
    float4* __restrict__ orow = reinterpret_cast<float4*>(out + row * (long long)ROW_D);

    const int t = threadIdx.x;

    // Load 16 floats/thread (4 x float4), coalesced: vec index t, t+256, t+512, t+768
    float4 v[4];
    float m = 0.0f;
#pragma unroll
    for (int i = 0; i < 4; ++i) {
        v[i] = xrow[t + i * BLOCK];
        m = fmaxf(m, fmaxf(fmaxf(fabsf(v[i].x), fabsf(v[i].y)),
                           fmaxf(fabsf(v[i].z), fabsf(v[i].w))));
    }

    // Wave-64 butterfly max reduction
#pragma unroll
    for (int off = 32; off > 0; off >>= 1)
        m = fmaxf(m, __shfl_xor(m, off));

    // Combine 4 waves via LDS
    __shared__ float smax[4];
    const int wave = t >> 6;
    const int lane = t & 63;
    if (lane == 0) smax[wave] = m;
    __syncthreads();
    const float gamma = fmaxf(fmaxf(smax[0], smax[1]), fmaxf(smax[2], smax[3]));
    const float denom = gamma + EPS_Q;

    // Quantize from registers and store. rintf = round-half-even (matches np.round).
    // True IEEE '/' (no reciprocal trick) so ties match the numpy reference bitwise.
#pragma unroll
    for (int i = 0; i < 4; ++i) {
        float4 o;
        o.x = rintf(v[i].x / denom);
        o.y = rintf(v[i].y / denom);
        o.z = rintf(v[i].z / denom);
        o.w = rintf(v[i].w / denom);
        orow[t + i * BLOCK] = o;
    }
}

extern "C" void kernel_launch(void* const* d_in, const int* in_sizes, int n_in,
                              void* d_out, int out_size, void* d_ws, size_t ws_size,
                              hipStream_t stream) {
    const float* x = (const float*)d_in[0];
    float* out = (float*)d_out;
    const int rows = in_sizes[0] / ROW_D;  // 8192
    qtern_kernel<<<rows, BLOCK, 0, stream>>>(x, out);
}